// Round 4
// baseline (89.943 us; speedup 1.0000x reference)
//
#include <hip/hip_runtime.h>
#include <hip/hip_bf16.h>
#include <stdint.h>

// GraphRec attention aggregator, fused. B=16384, D=50 neighbors, E=64.
// TWO waves per node (25 neighbors each) for gather-latency hiding; online
// softmax per wave + exact cross-wave merge via LDS. MFMA layers transposed.

#define BATCH 16384
#define DEG 50

typedef __attribute__((ext_vector_type(8))) short short8;   // 8 bf16 = 4 VGPR
typedef __attribute__((ext_vector_type(4))) float f32x4;

__device__ __forceinline__ short bf(float f) {
    __hip_bfloat16 h = __float2bfloat16(f);
    return *reinterpret_cast<short*>(&h);
}
__device__ __forceinline__ unsigned pk2(float a, float b) {
    union { unsigned u; unsigned short s[2]; } v;
    v.s[0] = (unsigned short)bf(a);
    v.s[1] = (unsigned short)bf(b);
    return v.u;
}
__device__ __forceinline__ float bf2f(short s) {
    union { float f; unsigned u; } v;
    v.u = (unsigned)(unsigned short)s << 16;
    return v.f;
}
__device__ __forceinline__ short8 cvt_row8(const float* p) {
    f32x4 a = *reinterpret_cast<const f32x4*>(p);
    f32x4 c = *reinterpret_cast<const f32x4*>(p + 4);
    union { short8 s; unsigned u[4]; } v;
    v.u[0] = pk2(a[0], a[1]); v.u[1] = pk2(a[2], a[3]);
    v.u[2] = pk2(c[0], c[1]); v.u[3] = pk2(c[2], c[3]);
    return v.s;
}

// ---- setup: pack W1^T / W2^T MFMA A-fragments (bf16) into d_ws, once ----
// frag f<16: W1 (kt=f>>2, t=f&3); frag 16+g: W2 (kt2=g>>2, t2=g&3).
// A layout (16x16x32): lane l holds A[l&15][8*(l>>4)+j], j=0..7
__global__ void pack_weights(const float* __restrict__ w1, const float* __restrict__ w2,
                             short8* __restrict__ ws) {
    const int f = blockIdx.x;            // 0..23
    const int lane = threadIdx.x;        // 0..63
    const int q = lane >> 4, r = lane & 15;
    const float* w = (f < 16) ? w1 : w2;
    const int g  = (f < 16) ? f : (f - 16);
    const int kt = g >> 2, t = g & 3;
    short8 s;
    #pragma unroll
    for (int j = 0; j < 8; ++j)
        s[j] = bf(w[(32*kt + 8*q + j)*64 + 16*t + r]);
    ws[f*64 + lane] = s;
}

__global__ __launch_bounds__(256, 4)
void graphrec_fused(const int* __restrict__ nodes, const int* __restrict__ neighbors,
                    const float* __restrict__ u_to_e,
                    const short8* __restrict__ wpk,
                    const float* __restrict__ b1, const float* __restrict__ b2,
                    const float* __restrict__ w3,
                    float* __restrict__ out)
{
    __shared__ short8 lds_a[24][64];                 // [0..15] W1 frags, [16..23] W2 frags
    __shared__ int    lds_nbr[2][64];                // per node
    __shared__ unsigned short lds_h1[4][1024];       // per-wave 16x64 bf16, XOR-swizzled
    __shared__ float  lds_m[2][2];                   // [node][wpart] running max
    __shared__ float  lds_s[2][2];                   // [node][wpart] rescaled denom
    __shared__ float  lds_agg[2][2][64];             // [node][wpart][embed]

    const int tid   = threadIdx.x;
    const int lane  = tid & 63;
    const int wid   = tid >> 6;
    const int q     = lane >> 4;
    const int r     = lane & 15;
    const int nloc  = wid >> 1;    // node within block
    const int wpart = wid & 1;     // which half of the neighbor set

    // block-copy pre-packed weight frags (24 KB, coalesced, L2-hot)
    #pragma unroll
    for (int i = 0; i < 6; ++i)
        reinterpret_cast<short8*>(lds_a)[tid + 256*i] = wpk[tid + 256*i];

    const int b    = blockIdx.x * 2 + nloc;
    const int node = nodes[b];
    if (wpart == 0)
        lds_nbr[nloc][lane] = (lane < DEG) ? neighbors[b * DEG + lane] : 0;
    __syncthreads();

    // ---- gather this wave's 2 m-tiles of neighbor embeddings as B-frags ----
    // global tile mt_g = 2*wpart + mtl; col m = 16*mt_g + r; k = 32*kt + 8q + j
    short8 xf[2][2];
    #pragma unroll
    for (int mtl = 0; mtl < 2; ++mtl) {
        const int nb = lds_nbr[nloc][16*(2*wpart + mtl) + r];
        const float* base = u_to_e + (size_t)nb * 64;
        xf[mtl][0] = cvt_row8(base + 8*q);
        xf[mtl][1] = cvt_row8(base + 32 + 8*q);
    }

    // ---- c_u[t] = b1 + W1[64:128]^T @ e_u (per wave; cols identical) ----
    f32x4 cu[4];
    {
        const float* ub = u_to_e + (size_t)node * 64;
        short8 xu0 = cvt_row8(ub + 8*q);
        short8 xu1 = cvt_row8(ub + 32 + 8*q);
        #pragma unroll
        for (int t = 0; t < 4; ++t) {
            cu[t] = *reinterpret_cast<const f32x4*>(b1 + 16*t + 4*q);
            cu[t] = __builtin_amdgcn_mfma_f32_16x16x32_bf16(lds_a[8  + t][lane], xu0, cu[t], 0, 0, 0);
            cu[t] = __builtin_amdgcn_mfma_f32_16x16x32_bf16(lds_a[12 + t][lane], xu1, cu[t], 0, 0, 0);
        }
    }

    f32x4 b2v[4], w3v[4];
    #pragma unroll
    for (int t = 0; t < 4; ++t) {
        b2v[t] = *reinterpret_cast<const f32x4*>(b2 + 16*t + 4*q);
        w3v[t] = *reinterpret_cast<const f32x4*>(w3 + 16*t + 4*q);
    }

    // ---- m-tile loop: layer1 -> relu -> LDS -> layer2 -> score -> online agg ----
    unsigned short* h1base = lds_h1[wid];
    float agg[16];
    #pragma unroll
    for (int i = 0; i < 16; ++i) agg[i] = 0.f;
    float m_run = -INFINITY, s_run = 0.f;

    #pragma unroll
    for (int mtl = 0; mtl < 2; ++mtl) {
        const int mt_g = 2*wpart + mtl;
        f32x4 acc[4] = { cu[0], cu[1], cu[2], cu[3] };
        #pragma unroll
        for (int kt = 0; kt < 2; ++kt)
            #pragma unroll
            for (int t = 0; t < 4; ++t)
                acc[t] = __builtin_amdgcn_mfma_f32_16x16x32_bf16(lds_a[kt*4 + t][lane], xf[mtl][kt], acc[t], 0, 0, 0);

        #pragma unroll
        for (int t = 0; t < 4; ++t) {
            unsigned lo = pk2(fmaxf(acc[t][0], 0.f), fmaxf(acc[t][1], 0.f));
            unsigned hi = pk2(fmaxf(acc[t][2], 0.f), fmaxf(acc[t][3], 0.f));
            int off = r * 128 + (((16*t + 4*q) * 2) ^ ((r & 7) << 4));
            *reinterpret_cast<uint2*>((char*)h1base + off) = make_uint2(lo, hi);
        }
        // layer 2 (same-wave LDS RAW, lgkmcnt-guarded in-order)
        f32x4 acc2[4];
        #pragma unroll
        for (int t2 = 0; t2 < 4; ++t2) acc2[t2] = (f32x4){0.f, 0.f, 0.f, 0.f};
        #pragma unroll
        for (int kt2 = 0; kt2 < 2; ++kt2) {
            int roff = r * 128 + (((32*kt2 + 8*q) * 2) ^ ((r & 7) << 4));
            short8 b2f = *reinterpret_cast<const short8*>((const char*)h1base + roff);
            #pragma unroll
            for (int t2 = 0; t2 < 4; ++t2)
                acc2[t2] = __builtin_amdgcn_mfma_f32_16x16x32_bf16(lds_a[16 + kt2*4 + t2][lane], b2f, acc2[t2], 0, 0, 0);
        }
        float sp = 0.f;
        #pragma unroll
        for (int t2 = 0; t2 < 4; ++t2)
            #pragma unroll
            for (int reg = 0; reg < 4; ++reg)
                sp += fmaxf(acc2[t2][reg] + b2v[t2][reg], 0.f) * w3v[t2][reg];
        sp += __shfl_xor(sp, 16, 64);
        sp += __shfl_xor(sp, 32, 64);   // score row m=16mt_g+r, replicated over q

        // online softmax update (rows >= DEG masked)
        float v = (mt_g < 3 || r < 2) ? sp : -INFINITY;
        float tm = v;
        tm = fmaxf(tm, __shfl_xor(tm, 1, 64));
        tm = fmaxf(tm, __shfl_xor(tm, 2, 64));
        tm = fmaxf(tm, __shfl_xor(tm, 4, 64));
        tm = fmaxf(tm, __shfl_xor(tm, 8, 64));
        float m_new = fmaxf(m_run, tm);
        float scale = __expf(m_run - m_new);
        float w = __expf(v - m_new);
        s_run = s_run * scale + w;
        #pragma unroll
        for (int kt = 0; kt < 2; ++kt)
            #pragma unroll
            for (int j = 0; j < 8; ++j)
                agg[kt*8 + j] = fmaf(agg[kt*8 + j], scale, w * bf2f(xf[mtl][kt][j]));
        m_run = m_new;
    }

    // ---- cross-wave merge: exchange max ----
    if (lane == 0) lds_m[nloc][wpart] = m_run;
    __syncthreads();
    const float m_all = fmaxf(lds_m[nloc][0], lds_m[nloc][1]);
    const float resc  = __expf(m_run - m_all);

    // denom: reduce s_run over r, rescale
    float s = s_run;
    s += __shfl_xor(s, 1, 64);
    s += __shfl_xor(s, 2, 64);
    s += __shfl_xor(s, 4, 64);
    s += __shfl_xor(s, 8, 64);
    s *= resc;

    // numerator: rescale + reduce over the 16 r-lanes within each q-group
    #pragma unroll
    for (int i = 0; i < 16; ++i) agg[i] *= resc;
    #pragma unroll
    for (int d = 1; d < 16; d <<= 1)
        #pragma unroll
        for (int i = 0; i < 16; ++i)
            agg[i] += __shfl_xor(agg[i], d, 64);

    if (r == 0) {
        #pragma unroll
        for (int kt = 0; kt < 2; ++kt)
            #pragma unroll
            for (int j = 0; j < 8; ++j)
                lds_agg[nloc][wpart][32*kt + 8*q + j] = agg[kt*8 + j];
        if (lane == 0) lds_s[nloc][wpart] = s;
    }
    __syncthreads();

    // ---- final combine + store (wave 0 of each node; lane = embed index) ----
    if (wpart == 0) {
        float num = lds_agg[nloc][0][lane] + lds_agg[nloc][1][lane];
        float inv = 1.f / (lds_s[nloc][0] + lds_s[nloc][1]);
        out[(size_t)b * 64 + lane] = num * inv;
    }
}

extern "C" void kernel_launch(void* const* d_in, const int* in_sizes, int n_in,
                              void* d_out, int out_size, void* d_ws, size_t ws_size,
                              hipStream_t stream) {
    const int*   nodes     = (const int*)d_in[0];
    const int*   neighbors = (const int*)d_in[1];
    const float* u_to_e    = (const float*)d_in[2];
    const float* w1        = (const float*)d_in[3];
    const float* b1        = (const float*)d_in[4];
    const float* w2        = (const float*)d_in[5];
    const float* b2        = (const float*)d_in[6];
    const float* w3        = (const float*)d_in[7];
    // d_in[8] = b3: constant shift, cancelled exactly by softmax — omitted.

    pack_weights<<<dim3(24), dim3(64), 0, stream>>>(w1, w2, (short8*)d_ws);
    graphrec_fused<<<dim3(BATCH / 2), dim3(256), 0, stream>>>(
        nodes, neighbors, u_to_e, (const short8*)d_ws, b1, b2, w3, (float*)d_out);
}

// Round 5
// 73.746 us; speedup vs baseline: 1.2196x; 1.2196x over previous
//
#include <hip/hip_runtime.h>
#include <hip/hip_bf16.h>
#include <stdint.h>

// GraphRec attention aggregator, fused. B=16384, D=50 neighbors, E=64.
// One wave per node. Neighbor-row gathers staged via global_load_lds (16B)
// into double-buffered LDS, 2 tiles in flight, counted vmcnt (T3/T4).
// H1^T = W1^T @ X^T via MFMA (transposed); e_u column hoisted to c_u;
// online softmax + in-register bf16 aggregation.

#define BATCH 16384
#define DEG 50

typedef __attribute__((ext_vector_type(8))) short short8;   // 8 bf16 = 4 VGPR
typedef __attribute__((ext_vector_type(4))) float f32x4;

__device__ __forceinline__ short bf(float f) {
    __hip_bfloat16 h = __float2bfloat16(f);       // RNE; pairs into v_cvt_pk_bf16_f32
    return *reinterpret_cast<short*>(&h);
}
__device__ __forceinline__ unsigned pk2(float a, float b) {
    union { unsigned u; unsigned short s[2]; } v;
    v.s[0] = (unsigned short)bf(a);
    v.s[1] = (unsigned short)bf(b);
    return v.u;
}
__device__ __forceinline__ float bf2f(short s) {
    union { float f; unsigned u; } v;
    v.u = (unsigned)(unsigned short)s << 16;
    return v.f;
}
__device__ __forceinline__ short8 pkrow(f32x4 a, f32x4 c) {
    union { short8 s; unsigned u[4]; } v;
    v.u[0] = pk2(a[0], a[1]); v.u[1] = pk2(a[2], a[3]);
    v.u[2] = pk2(c[0], c[1]); v.u[3] = pk2(c[2], c[3]);
    return v.s;
}
__device__ __forceinline__ short8 cvt_row8(const float* p) {
    f32x4 a = *reinterpret_cast<const f32x4*>(p);
    f32x4 c = *reinterpret_cast<const f32x4*>(p + 4);
    return pkrow(a, c);
}

// ---- setup: pack W1^T / W2^T MFMA A-fragments (bf16) into d_ws, once ----
// frag f<16: W1 (kt=f>>2, t=f&3); frag 16+g: W2 (kt2=g>>2, t2=g&3).
// A layout (16x16x32): lane l holds A[l&15][8*(l>>4)+j], j=0..7
__global__ void pack_weights(const float* __restrict__ w1, const float* __restrict__ w2,
                             short8* __restrict__ ws) {
    const int f = blockIdx.x;            // 0..23
    const int lane = threadIdx.x;        // 0..63
    const int q = lane >> 4, r = lane & 15;
    const float* w = (f < 16) ? w1 : w2;
    const int g  = (f < 16) ? f : (f - 16);
    const int kt = g >> 2, t = g & 3;
    short8 s;
    #pragma unroll
    for (int j = 0; j < 8; ++j)
        s[j] = bf(w[(32*kt + 8*q + j)*64 + 16*t + r]);
    ws[f*64 + lane] = s;
}

__global__ __launch_bounds__(256, 2)
void graphrec_fused(const int* __restrict__ nodes, const int* __restrict__ neighbors,
                    const float* __restrict__ u_to_e,
                    const short8* __restrict__ wpk,
                    const float* __restrict__ b1, const float* __restrict__ b2,
                    const float* __restrict__ w3,
                    float* __restrict__ out)
{
    __shared__ short8 lds_a[24][64];                 // 24 KB: [0..15] W1, [16..23] W2 frags
    __shared__ int    lds_nbr[4][64];                // 1 KB
    __shared__ unsigned short lds_h1[4][1024];       // 8 KB: per-wave 16x64 bf16, XOR-swizzled
    __shared__ float  lds_stage[4][2][1024];         // 32 KB: per-wave 2 x 4KB gather tiles

    const int tid  = threadIdx.x;
    const int lane = tid & 63;
    const int wid  = tid >> 6;
    const int q    = lane >> 4;
    const int r    = lane & 15;

    // block-copy pre-packed weight frags (24 KB, coalesced, L2-hot)
    #pragma unroll
    for (int i = 0; i < 6; ++i)
        reinterpret_cast<short8*>(lds_a)[tid + 256*i] = wpk[tid + 256*i];

    const int b    = blockIdx.x * 4 + wid;
    const int node = nodes[b];
    lds_nbr[wid][lane] = (lane < DEG) ? neighbors[b * DEG + lane] : 0;
    __syncthreads();

    int rowv[4];
    #pragma unroll
    for (int mt = 0; mt < 4; ++mt) rowv[mt] = lds_nbr[wid][16*mt + r];

    // ---- c_u[t] = b1 + W1[64:128]^T @ e_u (all global loads consumed BEFORE staging) ----
    f32x4 cu[4];
    {
        const float* ub = u_to_e + (size_t)node * 64;
        short8 xu0 = cvt_row8(ub + 8*q);
        short8 xu1 = cvt_row8(ub + 32 + 8*q);
        #pragma unroll
        for (int t = 0; t < 4; ++t) {
            cu[t] = *reinterpret_cast<const f32x4*>(b1 + 16*t + 4*q);
            cu[t] = __builtin_amdgcn_mfma_f32_16x16x32_bf16(lds_a[8  + t][lane], xu0, cu[t], 0, 0, 0);
            cu[t] = __builtin_amdgcn_mfma_f32_16x16x32_bf16(lds_a[12 + t][lane], xu1, cu[t], 0, 0, 0);
        }
    }
    f32x4 b2v[4], w3v[4];
    #pragma unroll
    for (int t = 0; t < 4; ++t) {
        b2v[t] = *reinterpret_cast<const f32x4*>(b2 + 16*t + 4*q);
        w3v[t] = *reinterpret_cast<const f32x4*>(w3 + 16*t + 4*q);
    }

    // ---- staged gather: tile mt = rows 16mt..16mt+15 (4 KB fp32) ----
    // instr c: lane (q,r) loads row rowv[mt], floats [4q+16c, +4) -> LDS dst+256c+4*lane.
    // read-back: lane (q,r) chunk cc at float offset (cc>>2)*256 + (cc&3)*64 + 4r.
    float* stg = &lds_stage[wid][0][0];
    #define ISSUE_TILE(MT) do {                                                          \
        const float* base_ = u_to_e + (size_t)rowv[MT] * 64 + 4*q;                       \
        float* dst_ = stg + ((MT) & 1) * 1024;                                           \
        _Pragma("unroll")                                                                \
        for (int c_ = 0; c_ < 4; ++c_)                                                   \
            __builtin_amdgcn_global_load_lds(                                            \
                (const __attribute__((address_space(1))) void*)(base_ + 16*c_),         \
                (__attribute__((address_space(3))) void*)(dst_ + 256*c_), 16, 0, 0);    \
    } while (0)

    __builtin_amdgcn_sched_barrier(0);
    ISSUE_TILE(0);
    ISSUE_TILE(1);
    __builtin_amdgcn_sched_barrier(0);

    unsigned short* h1base = lds_h1[wid];
    float agg[16];
    #pragma unroll
    for (int i = 0; i < 16; ++i) agg[i] = 0.f;
    float m_run = -INFINITY, s_run = 0.f;

    #pragma unroll
    for (int mt = 0; mt < 4; ++mt) {
        if (mt < 3) asm volatile("s_waitcnt vmcnt(4)" ::: "memory");
        else        asm volatile("s_waitcnt vmcnt(0)" ::: "memory");
        __builtin_amdgcn_sched_barrier(0);

        const float* bp  = stg + (mt & 1) * 1024;
        const int boff   = (q >> 1) * 256 + (q & 1) * 128 + 4*r;
        f32x4 A  = *reinterpret_cast<const f32x4*>(bp + boff);        // floats 8q..+3
        f32x4 Bv = *reinterpret_cast<const f32x4*>(bp + boff + 64);   // floats 8q+4..+7
        f32x4 C  = *reinterpret_cast<const f32x4*>(bp + boff + 512);  // floats 32+8q..+3
        f32x4 Dv = *reinterpret_cast<const f32x4*>(bp + boff + 576);  // floats 32+8q+4..+7
        short8 xf0 = pkrow(A, Bv);
        short8 xf1 = pkrow(C, Dv);

        // buffer consumed -> refill it now (loads fly under the whole compute below)
        if (mt < 2) ISSUE_TILE(mt + 2);

        f32x4 acc[4] = { cu[0], cu[1], cu[2], cu[3] };
        #pragma unroll
        for (int t = 0; t < 4; ++t) {
            acc[t] = __builtin_amdgcn_mfma_f32_16x16x32_bf16(lds_a[t][lane],     xf0, acc[t], 0, 0, 0);
            acc[t] = __builtin_amdgcn_mfma_f32_16x16x32_bf16(lds_a[4 + t][lane], xf1, acc[t], 0, 0, 0);
        }

        #pragma unroll
        for (int t = 0; t < 4; ++t) {
            unsigned lo = pk2(fmaxf(acc[t][0], 0.f), fmaxf(acc[t][1], 0.f));
            unsigned hi = pk2(fmaxf(acc[t][2], 0.f), fmaxf(acc[t][3], 0.f));
            int off = r * 128 + (((16*t + 4*q) * 2) ^ ((r & 7) << 4));
            *reinterpret_cast<uint2*>((char*)h1base + off) = make_uint2(lo, hi);
        }
        // layer 2 (same-wave LDS RAW, lgkmcnt-guarded in-order)
        f32x4 acc2[4];
        #pragma unroll
        for (int t2 = 0; t2 < 4; ++t2) acc2[t2] = (f32x4){0.f, 0.f, 0.f, 0.f};
        #pragma unroll
        for (int kt2 = 0; kt2 < 2; ++kt2) {
            int roff = r * 128 + (((32*kt2 + 8*q) * 2) ^ ((r & 7) << 4));
            short8 b2f = *reinterpret_cast<const short8*>((const char*)h1base + roff);
            #pragma unroll
            for (int t2 = 0; t2 < 4; ++t2)
                acc2[t2] = __builtin_amdgcn_mfma_f32_16x16x32_bf16(lds_a[16 + kt2*4 + t2][lane], b2f, acc2[t2], 0, 0, 0);
        }
        float sp = 0.f;
        #pragma unroll
        for (int t2 = 0; t2 < 4; ++t2)
            #pragma unroll
            for (int reg = 0; reg < 4; ++reg)
                sp += fmaxf(acc2[t2][reg] + b2v[t2][reg], 0.f) * w3v[t2][reg];
        sp += __shfl_xor(sp, 16, 64);
        sp += __shfl_xor(sp, 32, 64);   // score for row m=16mt+r, replicated over q

        // online softmax update (rows >= DEG masked)
        float v = (mt < 3 || r < 2) ? sp : -INFINITY;
        float tm = v;
        tm = fmaxf(tm, __shfl_xor(tm, 1, 64));
        tm = fmaxf(tm, __shfl_xor(tm, 2, 64));
        tm = fmaxf(tm, __shfl_xor(tm, 4, 64));
        tm = fmaxf(tm, __shfl_xor(tm, 8, 64));
        float m_new = fmaxf(m_run, tm);
        float scale = __expf(m_run - m_new);   // first iter: exp(-inf)=0, agg/s_run are 0
        float w = __expf(v - m_new);           // masked rows: exp(-inf)=0
        s_run = s_run * scale + w;
        #pragma unroll
        for (int kt = 0; kt < 2; ++kt)
            #pragma unroll
            for (int j = 0; j < 8; ++j) {
                float e = bf2f((kt == 0) ? xf0[j] : xf1[j]);
                agg[kt*8 + j] = fmaf(agg[kt*8 + j], scale, w * e);
            }
        m_run = m_new;
    }
    #undef ISSUE_TILE

    // ---- normalize + cross-lane reduce over r within each q-group ----
    float sum = s_run;
    sum += __shfl_xor(sum, 1, 64);
    sum += __shfl_xor(sum, 2, 64);
    sum += __shfl_xor(sum, 4, 64);
    sum += __shfl_xor(sum, 8, 64);
    float inv = 1.f / sum;
    #pragma unroll
    for (int i = 0; i < 16; ++i) agg[i] *= inv;
    #pragma unroll
    for (int d = 1; d < 16; d <<= 1)
        #pragma unroll
        for (int i = 0; i < 16; ++i)
            agg[i] += __shfl_xor(agg[i], d, 64);

    if (r == 0) {
        float* ob = out + (size_t)b * 64;
        *reinterpret_cast<f32x4*>(ob + 8*q)          = (f32x4){ agg[0],  agg[1],  agg[2],  agg[3]  };
        *reinterpret_cast<f32x4*>(ob + 8*q + 4)      = (f32x4){ agg[4],  agg[5],  agg[6],  agg[7]  };
        *reinterpret_cast<f32x4*>(ob + 32 + 8*q)     = (f32x4){ agg[8],  agg[9],  agg[10], agg[11] };
        *reinterpret_cast<f32x4*>(ob + 32 + 8*q + 4) = (f32x4){ agg[12], agg[13], agg[14], agg[15] };
    }
}

extern "C" void kernel_launch(void* const* d_in, const int* in_sizes, int n_in,
                              void* d_out, int out_size, void* d_ws, size_t ws_size,
                              hipStream_t stream) {
    const int*   nodes     = (const int*)d_in[0];
    const int*   neighbors = (const int*)d_in[1];
    const float* u_to_e    = (const float*)d_in[2];
    const float* w1        = (const float*)d_in[3];
    const float* b1        = (const float*)d_in[4];
    const float* w2        = (const float*)d_in[5];
    const float* b2        = (const float*)d_in[6];
    const float* w3        = (const float*)d_in[7];
    // d_in[8] = b3: constant shift, cancelled exactly by softmax — omitted.

    pack_weights<<<dim3(24), dim3(64), 0, stream>>>(w1, w2, (short8*)d_ws);
    graphrec_fused<<<dim3(BATCH / 4), dim3(256), 0, stream>>>(
        nodes, neighbors, u_to_e, (const short8*)d_ws, b1, b2, w3, (float*)d_out);
}

// Round 6
// 62.954 us; speedup vs baseline: 1.4287x; 1.1714x over previous
//
#include <hip/hip_runtime.h>
#include <hip/hip_bf16.h>
#include <stdint.h>

// GraphRec attention aggregator, fused. B=16384, D=50 neighbors, E=64.
// One wave per node. Neighbor rows staged via global_load_lds (16B, dense
// 64B-line requests) into two 2-KB half-tile slots per wave, pipelined one
// tile ahead with counted vmcnt. 3 blocks/CU (49 KB LDS). MFMA transposed
// layers; e_u hoisted to c_u; online softmax; in-register bf16 aggregation.

#define BATCH 16384
#define DEG 50

typedef __attribute__((ext_vector_type(8))) short short8;   // 8 bf16 = 4 VGPR
typedef __attribute__((ext_vector_type(4))) float f32x4;

__device__ __forceinline__ short bf(float f) {
    __hip_bfloat16 h = __float2bfloat16(f);       // RNE; pairs into v_cvt_pk_bf16_f32
    return *reinterpret_cast<short*>(&h);
}
__device__ __forceinline__ unsigned pk2(float a, float b) {
    union { unsigned u; unsigned short s[2]; } v;
    v.s[0] = (unsigned short)bf(a);
    v.s[1] = (unsigned short)bf(b);
    return v.u;
}
__device__ __forceinline__ float bf2f(short s) {
    union { float f; unsigned u; } v;
    v.u = (unsigned)(unsigned short)s << 16;
    return v.f;
}
__device__ __forceinline__ short8 pkrow(f32x4 a, f32x4 c) {
    union { short8 s; unsigned u[4]; } v;
    v.u[0] = pk2(a[0], a[1]); v.u[1] = pk2(a[2], a[3]);
    v.u[2] = pk2(c[0], c[1]); v.u[3] = pk2(c[2], c[3]);
    return v.s;
}
__device__ __forceinline__ short8 cvt_row8(const float* p) {
    f32x4 a = *reinterpret_cast<const f32x4*>(p);
    f32x4 c = *reinterpret_cast<const f32x4*>(p + 4);
    return pkrow(a, c);
}

// ---- setup: pack W1^T / W2^T MFMA A-fragments (bf16) into d_ws, once ----
// frag f<16: W1 (kt=f>>2, t=f&3); frag 16+g: W2 (kt2=g>>2, t2=g&3).
// A layout (16x16x32): lane l holds A[l&15][8*(l>>4)+j], j=0..7
__global__ void pack_weights(const float* __restrict__ w1, const float* __restrict__ w2,
                             short8* __restrict__ ws) {
    const int f = blockIdx.x;            // 0..23
    const int lane = threadIdx.x;        // 0..63
    const int q = lane >> 4, r = lane & 15;
    const float* w = (f < 16) ? w1 : w2;
    const int g  = (f < 16) ? f : (f - 16);
    const int kt = g >> 2, t = g & 3;
    short8 s;
    #pragma unroll
    for (int j = 0; j < 8; ++j)
        s[j] = bf(w[(32*kt + 8*q + j)*64 + 16*t + r]);
    ws[f*64 + lane] = s;
}

__global__ __launch_bounds__(256, 3)
void graphrec_fused(const int* __restrict__ nodes, const int* __restrict__ neighbors,
                    const float* __restrict__ u_to_e,
                    const short8* __restrict__ wpk,
                    const float* __restrict__ b1, const float* __restrict__ b2,
                    const float* __restrict__ w3,
                    float* __restrict__ out)
{
    __shared__ short8 lds_a[24][64];                 // 24 KB: [0..15] W1, [16..23] W2 frags
    __shared__ int    lds_nbr[4][64];                // 1 KB
    __shared__ unsigned short lds_h1[4][1024];       // 8 KB: per-wave 16x64 bf16, XOR-swizzled
    __shared__ float  lds_stage[4][2][512];          // 16 KB: per-wave 2 half-tile slots (2 KB)

    const int tid  = threadIdx.x;
    const int lane = tid & 63;
    const int wid  = tid >> 6;
    const int q    = lane >> 4;
    const int r    = lane & 15;

    // block-copy pre-packed weight frags (24 KB, coalesced, L3-hot)
    #pragma unroll
    for (int i = 0; i < 6; ++i)
        reinterpret_cast<short8*>(lds_a)[tid + 256*i] = wpk[tid + 256*i];

    const int b    = blockIdx.x * 4 + wid;
    const int node = nodes[b];
    lds_nbr[wid][lane] = (lane < DEG) ? neighbors[b * DEG + lane] : 0;
    __syncthreads();

    int rowv[4];
    #pragma unroll
    for (int mt = 0; mt < 4; ++mt) rowv[mt] = lds_nbr[wid][16*mt + r];

    // ---- c_u[t] = b1 + W1[64:128]^T @ e_u (all plain global loads issued+used here) ----
    f32x4 cu[4];
    {
        const float* ub = u_to_e + (size_t)node * 64;
        short8 xu0 = cvt_row8(ub + 8*q);
        short8 xu1 = cvt_row8(ub + 32 + 8*q);
        #pragma unroll
        for (int t = 0; t < 4; ++t) {
            cu[t] = *reinterpret_cast<const f32x4*>(b1 + 16*t + 4*q);
            cu[t] = __builtin_amdgcn_mfma_f32_16x16x32_bf16(lds_a[8  + t][lane], xu0, cu[t], 0, 0, 0);
            cu[t] = __builtin_amdgcn_mfma_f32_16x16x32_bf16(lds_a[12 + t][lane], xu1, cu[t], 0, 0, 0);
        }
    }
    f32x4 b2v[4], w3v[4];
    #pragma unroll
    for (int t = 0; t < 4; ++t) {
        b2v[t] = *reinterpret_cast<const f32x4*>(b2 + 16*t + 4*q);
        w3v[t] = *reinterpret_cast<const f32x4*>(w3 + 16*t + 4*q);
    }

    // ---- staged gather, half-tile (2 KB) granularity ----
    // half h (0..7): tile mt=h>>1, row-half hh=h&1 (floats 32*hh..+31), slot = h&1.
    // instr c (0,1): lane(q,r) loads row rowv[mt] floats [32*hh + 16*c + 4*q, +4)
    //   -> LDS slotbase + 256*c + 4*laneid   (DMA: uniform base + lane*16B)
    // readback: lane(q,r) float f'=8q of the half sits at 256*(q>>1)+128*(q&1)+4r.
    float* stg = &lds_stage[wid][0][0];
    #define ISSUE_HALF(H) do {                                                           \
        const float* base_ = u_to_e + (size_t)rowv[(H) >> 1] * 64 + 32*((H) & 1) + 4*q;  \
        float* dst_ = stg + ((H) & 1) * 512;                                             \
        _Pragma("unroll")                                                                \
        for (int c_ = 0; c_ < 2; ++c_)                                                   \
            __builtin_amdgcn_global_load_lds(                                            \
                (const __attribute__((address_space(1))) void*)(base_ + 16*c_),          \
                (__attribute__((address_space(3))) void*)(dst_ + 256*c_), 16, 0, 0);     \
    } while (0)

    __builtin_amdgcn_sched_barrier(0);
    ISSUE_HALF(0);
    ISSUE_HALF(1);
    __builtin_amdgcn_sched_barrier(0);

    unsigned short* h1base = lds_h1[wid];
    float agg[16];
    #pragma unroll
    for (int i = 0; i < 16; ++i) agg[i] = 0.f;
    float m_run = -INFINITY, s_run = 0.f;
    const int boff = 256*(q >> 1) + 128*(q & 1) + 4*r;

    #pragma unroll
    for (int mt = 0; mt < 4; ++mt) {
        // ---- slot 0: floats 0..31 of this tile's 16 rows ----
        if (mt < 3) asm volatile("s_waitcnt vmcnt(2)" ::: "memory");
        else        asm volatile("s_waitcnt vmcnt(2)" ::: "memory");
        __builtin_amdgcn_sched_barrier(0);
        f32x4 A  = *reinterpret_cast<const f32x4*>(stg + boff);
        f32x4 Bv = *reinterpret_cast<const f32x4*>(stg + boff + 64);
        short8 xf0 = pkrow(A, Bv);                    // lgkm-waited before use
        if (mt < 3) { ISSUE_HALF(2*mt + 2); }         // refill slot 0

        // ---- slot 1: floats 32..63 ----
        if (mt < 3) asm volatile("s_waitcnt vmcnt(2)" ::: "memory");
        else        asm volatile("s_waitcnt vmcnt(0)" ::: "memory");
        __builtin_amdgcn_sched_barrier(0);
        f32x4 C  = *reinterpret_cast<const f32x4*>(stg + 512 + boff);
        f32x4 Dv = *reinterpret_cast<const f32x4*>(stg + 512 + boff + 64);
        short8 xf1 = pkrow(C, Dv);
        if (mt < 3) { ISSUE_HALF(2*mt + 3); }         // refill slot 1

        // ---- layer 1 ----
        f32x4 acc[4] = { cu[0], cu[1], cu[2], cu[3] };
        #pragma unroll
        for (int t = 0; t < 4; ++t) {
            acc[t] = __builtin_amdgcn_mfma_f32_16x16x32_bf16(lds_a[t][lane],     xf0, acc[t], 0, 0, 0);
            acc[t] = __builtin_amdgcn_mfma_f32_16x16x32_bf16(lds_a[4 + t][lane], xf1, acc[t], 0, 0, 0);
        }

        #pragma unroll
        for (int t = 0; t < 4; ++t) {
            unsigned lo = pk2(fmaxf(acc[t][0], 0.f), fmaxf(acc[t][1], 0.f));
            unsigned hi = pk2(fmaxf(acc[t][2], 0.f), fmaxf(acc[t][3], 0.f));
            int off = r * 128 + (((16*t + 4*q) * 2) ^ ((r & 7) << 4));
            *reinterpret_cast<uint2*>((char*)h1base + off) = make_uint2(lo, hi);
        }
        // ---- layer 2 (same-wave LDS RAW, lgkmcnt-guarded in-order) ----
        f32x4 acc2[4];
        #pragma unroll
        for (int t2 = 0; t2 < 4; ++t2) acc2[t2] = (f32x4){0.f, 0.f, 0.f, 0.f};
        #pragma unroll
        for (int kt2 = 0; kt2 < 2; ++kt2) {
            int roff = r * 128 + (((32*kt2 + 8*q) * 2) ^ ((r & 7) << 4));
            short8 b2f = *reinterpret_cast<const short8*>((const char*)h1base + roff);
            #pragma unroll
            for (int t2 = 0; t2 < 4; ++t2)
                acc2[t2] = __builtin_amdgcn_mfma_f32_16x16x32_bf16(lds_a[16 + kt2*4 + t2][lane], b2f, acc2[t2], 0, 0, 0);
        }
        float sp = 0.f;
        #pragma unroll
        for (int t2 = 0; t2 < 4; ++t2)
            #pragma unroll
            for (int reg = 0; reg < 4; ++reg)
                sp += fmaxf(acc2[t2][reg] + b2v[t2][reg], 0.f) * w3v[t2][reg];
        sp += __shfl_xor(sp, 16, 64);
        sp += __shfl_xor(sp, 32, 64);   // score for row m=16mt+r, replicated over q

        // ---- online softmax update (rows >= DEG masked) ----
        float v = (mt < 3 || r < 2) ? sp : -INFINITY;
        float tm = v;
        tm = fmaxf(tm, __shfl_xor(tm, 1, 64));
        tm = fmaxf(tm, __shfl_xor(tm, 2, 64));
        tm = fmaxf(tm, __shfl_xor(tm, 4, 64));
        tm = fmaxf(tm, __shfl_xor(tm, 8, 64));
        float m_new = fmaxf(m_run, tm);
        float scale = __expf(m_run - m_new);   // first iter: exp(-inf)=0, agg/s_run are 0
        float w = __expf(v - m_new);           // masked rows: exp(-inf)=0
        s_run = s_run * scale + w;
        #pragma unroll
        for (int kt = 0; kt < 2; ++kt)
            #pragma unroll
            for (int j = 0; j < 8; ++j) {
                float e = bf2f((kt == 0) ? xf0[j] : xf1[j]);
                agg[kt*8 + j] = fmaf(agg[kt*8 + j], scale, w * e);
            }
        m_run = m_new;
    }
    #undef ISSUE_HALF

    // ---- normalize + cross-lane reduce over r within each q-group ----
    float sum = s_run;
    sum += __shfl_xor(sum, 1, 64);
    sum += __shfl_xor(sum, 2, 64);
    sum += __shfl_xor(sum, 4, 64);
    sum += __shfl_xor(sum, 8, 64);
    float inv = 1.f / sum;
    #pragma unroll
    for (int i = 0; i < 16; ++i) agg[i] *= inv;
    #pragma unroll
    for (int d = 1; d < 16; d <<= 1)
        #pragma unroll
        for (int i = 0; i < 16; ++i)
            agg[i] += __shfl_xor(agg[i], d, 64);

    if (r == 0) {
        float* ob = out + (size_t)b * 64;
        *reinterpret_cast<f32x4*>(ob + 8*q)          = (f32x4){ agg[0],  agg[1],  agg[2],  agg[3]  };
        *reinterpret_cast<f32x4*>(ob + 8*q + 4)      = (f32x4){ agg[4],  agg[5],  agg[6],  agg[7]  };
        *reinterpret_cast<f32x4*>(ob + 32 + 8*q)     = (f32x4){ agg[8],  agg[9],  agg[10], agg[11] };
        *reinterpret_cast<f32x4*>(ob + 32 + 8*q + 4) = (f32x4){ agg[12], agg[13], agg[14], agg[15] };
    }
}

extern "C" void kernel_launch(void* const* d_in, const int* in_sizes, int n_in,
                              void* d_out, int out_size, void* d_ws, size_t ws_size,
                              hipStream_t stream) {
    const int*   nodes     = (const int*)d_in[0];
    const int*   neighbors = (const int*)d_in[1];
    const float* u_to_e    = (const float*)d_in[2];
    const float* w1        = (const float*)d_in[3];
    const float* b1        = (const float*)d_in[4];
    const float* w2        = (const float*)d_in[5];
    const float* b2        = (const float*)d_in[6];
    const float* w3        = (const float*)d_in[7];
    // d_in[8] = b3: constant shift, cancelled exactly by softmax — omitted.

    pack_weights<<<dim3(24), dim3(64), 0, stream>>>(w1, w2, (short8*)d_ws);
    graphrec_fused<<<dim3(BATCH / 4), dim3(256), 0, stream>>>(
        nodes, neighbors, u_to_e, (const short8*)d_ws, b1, b2, w3, (float*)d_out);
}